// Round 3
// baseline (347.142 us; speedup 1.0000x reference)
//
#include <hip/hip_runtime.h>
#include <hip/hip_bf16.h>
#include <stdint.h>

namespace {
constexpr int kH = 64;
constexpr int kIn = 9;
constexpr int kSrcLen = 7;
constexpr int kPredLen = 10;
constexpr int kRows = 64;        // batch rows per block (r0-proven ILP: 4 chunks/wave)
constexpr int kThreads = 256;    // 4 waves: wave w owns gate-cols w*16..w*16+15
constexpr int kChunks = kRows / 16;    // 4 row-chunks per wave
constexpr int kOutW = kPredLen * kIn;  // 90
// A (h part): fragment-contiguous f16, 8 k-blocks (k 0..63), element
// (blk,row,e) at (blk*kRows+row)*8+e. x/bias come straight from GLOBAL as
// fragments (no LDS x panel) -> LDS = 16,384 B declared -> ~29.5KB reported
// -> 5 blocks/CU LDS cap (was 4; grid is 4/CU so we finally have slack).
constexpr int kABlk = 8;
constexpr int kASz = kABlk * kRows * 8;   // 4096 halves = 8192 B per buffer

constexpr float kLog2e = 1.4426950408889634f;

typedef __attribute__((ext_vector_type(8))) _Float16 frag_a;   // K=32 frag (4 VGPRs)
typedef __attribute__((ext_vector_type(4))) _Float16 frag_a2;  // K=16 frag (2 VGPRs)
typedef __attribute__((ext_vector_type(4))) float frag_cd;     // 4 fp32 acc

__device__ __forceinline__ float fast_rcp(float x) { return __builtin_amdgcn_rcpf(x); }
__device__ __forceinline__ float exp2_f(float x) { return __builtin_amdgcn_exp2f(x); }
// x PRE-SCALED by log2e (folded into weights): sigmoid = 1/(1+2^-x)
__device__ __forceinline__ float sigmoid_pre(float x) { return fast_rcp(1.0f + exp2_f(-x)); }
// x PRE-SCALED by 2*log2e: tanh = 1 - 2/(2^x + 1)
__device__ __forceinline__ float tanh_pre(float x) { return 1.0f - 2.0f * fast_rcp(exp2_f(x) + 1.0f); }
// unscaled input (cell state)
__device__ __forceinline__ float tanh_f(float x) { return tanh_pre(x * (2.0f * kLog2e)); }

__device__ __forceinline__ float ldf(const void* p, int i, int isbf) {
  if (isbf) {
    uint32_t w = ((uint32_t)((const uint16_t*)p)[i]) << 16;
    float f; __builtin_memcpy(&f, &w, 4); return f;
  }
  return ((const float*)p)[i];
}
}  // namespace

// Detect whether inputs are bf16 or fp32 by sampling src.
extern "C" __global__ void detect_dtype_kernel(const uint16_t* __restrict__ src_u16,
                                               int* __restrict__ flag) {
  const int t = threadIdx.x;
  int bad = 0;
  for (int i = t; i < 256; i += 64) {
    const uint16_t u = src_u16[i];
    const uint32_t e = (u >> 7) & 0xFF;
    const int plausible = (u == 0) || (e >= 100 && e <= 150);
    bad += !plausible;
  }
#pragma unroll
  for (int off = 32; off; off >>= 1) bad += __shfl_down(bad, off, 64);
  if (t == 0) *flag = (bad < 64) ? 1 : 0;
}

extern "C" __global__ void __launch_bounds__(kThreads)
// min 5 waves/EU -> RA budget 102 unified regs. Estimated steady demand:
// encoder bm0/1/2(40) + c_st(16) + xf(8) + acc(16) + a0/a1(8) + addr(~10) ~ 98;
// decoder (folded) bm0/1(32) + fm(9) + beff(4) + c_st(16) + acc+a0a1(24) ~ 93.
// 5 waves/SIMD = 20 waves/CU = 5 blocks/CU VGPR cap; LDS cap also 5.
// Grid = 4 blocks/CU of work -> residency slack (r0/r2 were exact-fit, ~35% occ).
// TRIPWIRE: if FETCH_SIZE balloons past ~10 MB the 102-reg budget spilled ->
// fall back to (4,8). NEVER (8,8): 64-reg cap = 1.5 GB scratch (round 1).
__attribute__((amdgpu_waves_per_eu(5, 8)))
lstm_seq2seq_kernel(const void* __restrict__ src,
                    const void* __restrict__ enc_Wih,
                    const void* __restrict__ enc_Whh,
                    const void* __restrict__ enc_b,
                    const void* __restrict__ dec_Wih,
                    const void* __restrict__ dec_Whh,
                    const void* __restrict__ dec_b,
                    const void* __restrict__ fc_W,
                    const void* __restrict__ fc_b,
                    void* __restrict__ out,
                    const int* __restrict__ flag) {
  __shared__ __align__(16) _Float16 a_m[2][kASz];   // h, double-buffered, 16 KB total

  const int tid = threadIdx.x;
  const int lane = tid & 63;
  const int wave = tid >> 6;       // 0..3
  const int quad = lane >> 4;
  const int half = lane & 15;
  const int row0 = blockIdx.x * kRows;
  const int isbf = *flag;  // grid-uniform
  const int col = wave * 16 + half;  // hidden column owned in activation phase

  // ---- init: h buffers zero ----
  for (int i = tid; i < kASz; i += kThreads) {
    a_m[0][i] = (_Float16)0.0f;
    a_m[1][i] = (_Float16)0.0f;
  }

  // ---- persistent per-thread state: cell state for 4 chunks ----
  float c_st[4 * kChunks];
#pragma unroll
  for (int i = 0; i < 4 * kChunks; ++i) c_st[i] = 0.0f;

  // B fragments: nt = GATE TYPE (i,f,g,o), col = wave*16+half.
  // bm0/bm1[nt] = K-tiles 0,1 (Whh, K=32 each); bm2[nt] = K-tile 2 (Wih+bias, K=16).
  // PRE-SCALED: sigmoid gates (i,f,o) by log2e, tanh gate (g) by 2*log2e.
  frag_a bm0[4], bm1[4];
  frag_a2 bm2[4];
  float beff[4] = {0.f, 0.f, 0.f, 0.f};  // folded decoder bias (steps 2+)

  auto load_gate_frags = [&](const void* Whh, const void* Wih, const void* bv) {
#pragma unroll
    for (int nt = 0; nt < 4; ++nt) {
      const float scale = (nt == 2) ? (2.0f * kLog2e) : kLog2e;
      const int n = nt * kH + col;
      frag_a f0, f1;
#pragma unroll
      for (int j = 0; j < 8; ++j) {
        f0[j] = (_Float16)(scale * ldf(Whh, n * kH + (quad * 8 + j), isbf));
        f1[j] = (_Float16)(scale * ldf(Whh, n * kH + (32 + quad * 8 + j), isbf));
      }
      bm0[nt] = f0;
      bm1[nt] = f1;
      frag_a2 f2;
#pragma unroll
      for (int j = 0; j < 4; ++j) {
        const int k2 = quad * 4 + j;  // 0..15, global k = 64 + k2
        float v = 0.0f;
        if (k2 < kIn) v = ldf(Wih, n * kIn + k2, isbf);
        else if (k2 == kIn) v = ldf(bv, n, isbf);  // bias column (A supplies 1.0)
        f2[j] = (_Float16)(scale * v);
      }
      bm2[nt] = f2;
    }
  };

  // x fragments straight from global (no LDS round-trip). Lane (quad,half) of
  // chunk ch supplies A[row=ch*16+half][k=quad*4+j]; k 0..8 = x, k==9 = 1.0
  // (bias), rest 0. src tile is 16KB/block -> L2-hot after first touch.
  auto load_xfrags = [&](int s, frag_a2 (&xf)[kChunks]) {
#pragma unroll
    for (int ch = 0; ch < kChunks; ++ch) {
      frag_a2 f = {(_Float16)0.f, (_Float16)0.f, (_Float16)0.f, (_Float16)0.f};
      const int r = row0 + ch * 16 + half;
      const int base = r * (kSrcLen * kIn) + s * kIn;
      if (quad < 2) {
#pragma unroll
        for (int j = 0; j < 4; ++j) f[j] = (_Float16)ldf(src, base + quad * 4 + j, isbf);
      } else if (quad == 2) {
        f[0] = (_Float16)ldf(src, base + 8, isbf);  // x8
        f[1] = (_Float16)1.0f;                      // bias slot (k==9)
      }
      xf[ch] = f;
    }
  };

  // One LSTM step: read h from buf[cur], write h' into buf[cur^1]. No barrier.
  // use_x: encoder / first decoder step (3 MFMAs, bias via bm2).
  // !use_x: folded decoder recurrence (2 MFMAs, bias via beff acc-init).
  auto lstm_step = [&](int cur, const frag_a2* xf, bool use_x) {
#pragma unroll 1
    for (int ch = 0; ch < kChunks; ++ch) {
      const int r = ch * 16 + half;
      const frag_a a0 = *(const frag_a*)&a_m[cur][((0 * 4 + quad) * kRows + r) * 8];
      const frag_a a1 = *(const frag_a*)&a_m[cur][((1 * 4 + quad) * kRows + r) * 8];

      frag_cd acc[4];
#pragma unroll
      for (int nt = 0; nt < 4; ++nt) {
        frag_cd a;
        if (use_x) a = (frag_cd){0.f, 0.f, 0.f, 0.f};
        else a = (frag_cd){beff[nt], beff[nt], beff[nt], beff[nt]};
        a = __builtin_amdgcn_mfma_f32_16x16x32_f16(a0, bm0[nt], a, 0, 0, 0);
        a = __builtin_amdgcn_mfma_f32_16x16x32_f16(a1, bm1[nt], a, 0, 0, 0);
        if (use_x) a = __builtin_amdgcn_mfma_f32_16x16x16f16(xf[ch], bm2[nt], a, 0, 0, 0);
        acc[nt] = a;
      }

#pragma unroll
      for (int j = 0; j < 4; ++j) {
        const float gi = acc[0][j];
        const float gf = acc[1][j];
        const float gg = acc[2][j];
        const float go = acc[3][j];
        float c = c_st[ch * 4 + j];
        c = fmaf(sigmoid_pre(gf), c, sigmoid_pre(gi) * tanh_pre(gg));
        c_st[ch * 4 + j] = c;
        const float h = sigmoid_pre(go) * tanh_f(c);
        const int rr = ch * 16 + quad * 4 + j;
        a_m[cur ^ 1][(((col >> 3) * kRows) + rr) * 8 + (col & 7)] = (_Float16)h;
      }
    }
  };

  // ================= ENCODER =================
  load_gate_frags(enc_Whh, enc_Wih, enc_b);
  __syncthreads();  // a_m init visible

  int cur = 0;
  frag_a2 xf[kChunks];
#pragma unroll 1
  for (int s = 0; s < kSrcLen; ++s) {
    load_xfrags(s, xf);
    lstm_step(cur, xf, true);
    __syncthreads();
    cur ^= 1;
  }

  // ================= DECODER =================
  // Step 1 uses x_last = src[:, -1, :] through the plain dec weights.
  load_gate_frags(dec_Whh, dec_Wih, dec_b);
  load_xfrags(kSrcLen - 1, xf);
  lstm_step(cur, xf, true);
  __syncthreads();
  cur ^= 1;

  // ---- fold the pred->x feedback into the recurrence (steps 2..10):
  // gates = h @ (Whh + Wih@fc_W)^T + (b + Wih@fc_b), all pre-scaled.
  // bm0/bm1 already hold scale*Whh; add scale*(Wih@fc_W) elementwise.
  // One-time, all loads L2-hot (fc_W 2.25KB, dec_Wih 9KB).
#pragma unroll 1
  for (int nt = 0; nt < 4; ++nt) {
    const float scale = (nt == 2) ? (2.0f * kLog2e) : kLog2e;
    const int n = nt * kH + col;
    float wih_s[kIn];
#pragma unroll
    for (int j = 0; j < kIn; ++j) wih_s[j] = scale * ldf(dec_Wih, n * kIn + j, isbf);
    frag_a f0 = bm0[nt], f1 = bm1[nt];
#pragma unroll 1
    for (int e = 0; e < 8; ++e) {
      const int k0 = quad * 8 + e;
      const int k1 = 32 + quad * 8 + e;
      float a0 = (float)f0[e], a1 = (float)f1[e];
#pragma unroll
      for (int j = 0; j < kIn; ++j) {
        a0 = fmaf(wih_s[j], ldf(fc_W, j * kH + k0, isbf), a0);
        a1 = fmaf(wih_s[j], ldf(fc_W, j * kH + k1, isbf), a1);
      }
      f0[e] = (_Float16)a0;
      f1[e] = (_Float16)a1;
    }
    bm0[nt] = f0;
    bm1[nt] = f1;
    float be = scale * ldf(dec_b, n, isbf);
#pragma unroll
    for (int j = 0; j < kIn; ++j) be = fmaf(wih_s[j], ldf(fc_b, j, isbf), be);
    beff[nt] = be;
  }

  // fc head fragments (bm2 is dead now; RA reuses those regs).
  frag_a fm[2];
#pragma unroll
  for (int kt = 0; kt < 2; ++kt) {
    frag_a f;
#pragma unroll
    for (int j = 0; j < 8; ++j) {
      const int k = kt * 32 + quad * 8 + j;
      f[j] = (half < kIn) ? (_Float16)ldf(fc_W, half * kH + k, isbf) : (_Float16)0.0f;
    }
    fm[kt] = f;
  }
  const float fcb = (half < kIn) ? ldf(fc_b, half, isbf) : 0.0f;

  // fc head: wave w handles rows [w*16, w*16+16) of buf[cb]. Output-only
  // (no feedback scatter -> no extra barrier, fewer LDS bank conflicts).
  auto fc_head = [&](int t, int cb) {
    const int r = wave * 16 + half;
    const frag_a a0 = *(const frag_a*)&a_m[cb][((0 * 4 + quad) * kRows + r) * 8];
    const frag_a a1 = *(const frag_a*)&a_m[cb][((1 * 4 + quad) * kRows + r) * 8];
    frag_cd p = {fcb, fcb, fcb, fcb};
    p = __builtin_amdgcn_mfma_f32_16x16x32_f16(a0, fm[0], p, 0, 0, 0);
    p = __builtin_amdgcn_mfma_f32_16x16x32_f16(a1, fm[1], p, 0, 0, 0);
    if (half < kIn) {
#pragma unroll
      for (int j = 0; j < 4; ++j) {
        const int rr = wave * 16 + quad * 4 + j;
        const int oidx = (row0 + rr) * kOutW + t * kIn + half;
        if (isbf) ((__hip_bfloat16*)out)[oidx] = __float2bfloat16(p[j]);
        else ((float*)out)[oidx] = p[j];
      }
    }
  };

  // pred(0): h after decoder step 1 sits in a_m[cur]; safe to read while
  // step 2 writes a_m[cur^1] (different buffer, barrier'd before reuse).
  fc_head(0, cur);

#pragma unroll 1
  for (int t = 1; t < kPredLen; ++t) {
    lstm_step(cur, nullptr, false);
    __syncthreads();
    cur ^= 1;
    fc_head(t, cur);
  }
}

extern "C" void kernel_launch(void* const* d_in, const int* in_sizes, int n_in,
                              void* d_out, int out_size, void* d_ws, size_t ws_size,
                              hipStream_t stream) {
  (void)n_in; (void)ws_size; (void)out_size;
  int* flag = (int*)d_ws;

  hipLaunchKernelGGL(detect_dtype_kernel, dim3(1), dim3(64), 0, stream,
                     (const uint16_t*)d_in[0], flag);

  const int b_total = in_sizes[0] / (kSrcLen * kIn);
  const int grid = b_total / kRows;  // B=65536 -> 1024 blocks = 4 per CU of work

  hipLaunchKernelGGL(lstm_seq2seq_kernel, dim3(grid), dim3(kThreads), 0, stream,
                     d_in[0], d_in[1], d_in[2], d_in[3], d_in[4], d_in[5],
                     d_in[6], d_in[7], d_in[8], d_out, flag);
}

// Round 6
// 343.334 us; speedup vs baseline: 1.0111x; 1.0111x over previous
//
#include <hip/hip_runtime.h>
#include <hip/hip_bf16.h>
#include <stdint.h>

namespace {
constexpr int kH = 64;
constexpr int kIn = 9;
constexpr int kSrcLen = 7;
constexpr int kPredLen = 10;
constexpr int kRows = 64;        // batch rows per block (r0-proven ILP: 4 chunks/wave)
constexpr int kThreads = 256;    // 4 waves: wave w owns gate-cols w*16..w*16+15
constexpr int kChunks = kRows / 16;    // 4 row-chunks per wave
constexpr int kOutW = kPredLen * kIn;  // 90
// A (h part): fragment-contiguous f16 in TWO planes (hi + lo residual):
// h = h_hi + h_lo with h_lo = f16(h32 - h_hi). Both planes share the layout
// (blk,row,e) at (blk*kRows+row)*8+e. The lo plane feeds 2 extra MFMAs per
// gate REUSING bm0/bm1 -> h enters the matmul at ~f32 precision with zero
// extra persistent registers. This is the accuracy fix for the fold's
// threshold-straddling error (r3 pass / r4+r5 fail were codegen luck).
constexpr int kABlk = 8;
constexpr int kASz = kABlk * kRows * 8;   // 4096 halves = 8192 B per plane per buffer

constexpr float kLog2e = 1.4426950408889634f;

typedef __attribute__((ext_vector_type(8))) _Float16 frag_a;   // K=32 frag (4 VGPRs)
typedef __attribute__((ext_vector_type(4))) _Float16 frag_a2;  // K=16 frag (2 VGPRs)
typedef __attribute__((ext_vector_type(4))) float frag_cd;     // 4 fp32 acc

__device__ __forceinline__ float fast_rcp(float x) { return __builtin_amdgcn_rcpf(x); }
__device__ __forceinline__ float exp2_f(float x) { return __builtin_amdgcn_exp2f(x); }
// x PRE-SCALED by log2e (folded into weights): sigmoid = 1/(1+2^-x)
__device__ __forceinline__ float sigmoid_pre(float x) { return fast_rcp(1.0f + exp2_f(-x)); }
// x PRE-SCALED by 2*log2e: tanh = 1 - 2/(2^x + 1)
__device__ __forceinline__ float tanh_pre(float x) { return 1.0f - 2.0f * fast_rcp(exp2_f(x) + 1.0f); }
// unscaled input (cell state)
__device__ __forceinline__ float tanh_f(float x) { return tanh_pre(x * (2.0f * kLog2e)); }

__device__ __forceinline__ float ldf(const void* p, int i, int isbf) {
  if (isbf) {
    uint32_t w = ((uint32_t)((const uint16_t*)p)[i]) << 16;
    float f; __builtin_memcpy(&f, &w, 4); return f;
  }
  return ((const float*)p)[i];
}
}  // namespace

// Detect whether inputs are bf16 or fp32 by sampling src.
extern "C" __global__ void detect_dtype_kernel(const uint16_t* __restrict__ src_u16,
                                               int* __restrict__ flag) {
  const int t = threadIdx.x;
  int bad = 0;
  for (int i = t; i < 256; i += 64) {
    const uint16_t u = src_u16[i];
    const uint32_t e = (u >> 7) & 0xFF;
    const int plausible = (u == 0) || (e >= 100 && e <= 150);
    bad += !plausible;
  }
#pragma unroll
  for (int off = 32; off; off >>= 1) bad += __shfl_down(bad, off, 64);
  if (t == 0) *flag = (bad < 64) ? 1 : 0;
}

extern "C" __global__ void __launch_bounds__(kThreads)
// (4,8): min 4 waves/EU -> 128-unified-reg budget. PROVEN spill-free region
// (r0: 60 arch + 64 acc). ESTABLISHED FAILURES: (8,8) -> 1.5 GB scratch (r1);
// (5,8) -> 0.5 GB scratch (r3). Steady-state demand here ~112 (h-split adds
// only 2 transient lo-fragments; bias moved from bm2 column to f32 bacc).
// TRIPWIRE: FETCH_SIZE >> 10 MB means spill -> shrink, don't re-budget.
__attribute__((amdgpu_waves_per_eu(4, 8)))
lstm_seq2seq_kernel(const void* __restrict__ src,
                    const void* __restrict__ enc_Wih,
                    const void* __restrict__ enc_Whh,
                    const void* __restrict__ enc_b,
                    const void* __restrict__ dec_Wih,
                    const void* __restrict__ dec_Whh,
                    const void* __restrict__ dec_b,
                    const void* __restrict__ fc_W,
                    const void* __restrict__ fc_b,
                    void* __restrict__ out,
                    const int* __restrict__ flag) {
  __shared__ __align__(16) _Float16 a_mh[2][kASz];  // h hi plane, double-buffered
  __shared__ __align__(16) _Float16 a_ml[2][kASz];  // h lo-residual plane

  const int tid = threadIdx.x;
  const int lane = tid & 63;
  const int wave = tid >> 6;       // 0..3
  const int quad = lane >> 4;
  const int half = lane & 15;
  const int row0 = blockIdx.x * kRows;
  const int isbf = *flag;  // grid-uniform
  const int col = wave * 16 + half;  // hidden column owned in activation phase

  // ---- init: both h planes zero (h0 == 0) ----
  for (int i = tid; i < kASz; i += kThreads) {
    a_mh[0][i] = (_Float16)0.0f;
    a_mh[1][i] = (_Float16)0.0f;
    a_ml[0][i] = (_Float16)0.0f;
    a_ml[1][i] = (_Float16)0.0f;
  }

  // ---- persistent per-thread state: cell state for 4 chunks ----
  float c_st[4 * kChunks];
#pragma unroll
  for (int i = 0; i < 4 * kChunks; ++i) c_st[i] = 0.0f;

  // B fragments: nt = GATE TYPE (i,f,g,o), col = wave*16+half.
  // bm0/bm1[nt] = K-tiles 0,1 (Whh, K=32 each); bm2[nt] = K-tile 2 (Wih, K=16,
  // bias column REMOVED -> bias lives in f32 bacc, added via acc-init).
  // PRE-SCALED: sigmoid gates (i,f,o) by log2e, tanh gate (g) by 2*log2e.
  frag_a bm0[4], bm1[4];
  frag_a2 bm2[4];
  float bacc[4] = {0.f, 0.f, 0.f, 0.f};  // f32 bias (enc b / dec b / folded beff)

  auto load_gate_frags = [&](const void* Whh, const void* Wih, const void* bv) {
#pragma unroll
    for (int nt = 0; nt < 4; ++nt) {
      const float scale = (nt == 2) ? (2.0f * kLog2e) : kLog2e;
      const int n = nt * kH + col;
      frag_a f0, f1;
#pragma unroll
      for (int j = 0; j < 8; ++j) {
        f0[j] = (_Float16)(scale * ldf(Whh, n * kH + (quad * 8 + j), isbf));
        f1[j] = (_Float16)(scale * ldf(Whh, n * kH + (32 + quad * 8 + j), isbf));
      }
      bm0[nt] = f0;
      bm1[nt] = f1;
      frag_a2 f2;
#pragma unroll
      for (int j = 0; j < 4; ++j) {
        const int k2 = quad * 4 + j;  // 0..15, global k = 64 + k2
        float v = 0.0f;
        if (k2 < kIn) v = ldf(Wih, n * kIn + k2, isbf);
        f2[j] = (_Float16)(scale * v);
      }
      bm2[nt] = f2;
      bacc[nt] = scale * ldf(bv, n, isbf);  // f32 bias via acc-init (exact)
    }
  };

  // x fragments straight from global (no LDS round-trip). Lane (quad,half) of
  // chunk ch supplies A[row=ch*16+half][k=quad*4+j]; k 0..8 = x, rest 0.
  // src tile is 16KB/block -> L2-hot after first touch.
  auto load_xfrags = [&](int s, frag_a2 (&xf)[kChunks]) {
#pragma unroll
    for (int ch = 0; ch < kChunks; ++ch) {
      frag_a2 f = {(_Float16)0.f, (_Float16)0.f, (_Float16)0.f, (_Float16)0.f};
      const int r = row0 + ch * 16 + half;
      const int base = r * (kSrcLen * kIn) + s * kIn;
      if (quad < 2) {
#pragma unroll
        for (int j = 0; j < 4; ++j) f[j] = (_Float16)ldf(src, base + quad * 4 + j, isbf);
      } else if (quad == 2) {
        f[0] = (_Float16)ldf(src, base + 8, isbf);  // x8
      }
      xf[ch] = f;
    }
  };

  // One LSTM step: read h (hi+lo) from buf[cur], write h' into buf[cur^1].
  // No barrier inside. use_x: encoder / first decoder step (adds K=16 x MFMA).
  // !use_x: folded decoder recurrence (bacc holds the folded bias).
  // h-split: gates = W@h_hi + W@h_lo reuses bm0/bm1 -> h at ~f32 precision.
  auto lstm_step = [&](int cur, const frag_a2* xf, bool use_x) {
#pragma unroll 1
    for (int ch = 0; ch < kChunks; ++ch) {
      const int r = ch * 16 + half;
      const int i0 = ((0 * 4 + quad) * kRows + r) * 8;
      const int i1 = ((1 * 4 + quad) * kRows + r) * 8;
      const frag_a a0 = *(const frag_a*)&a_mh[cur][i0];
      const frag_a a1 = *(const frag_a*)&a_mh[cur][i1];
      const frag_a a0l = *(const frag_a*)&a_ml[cur][i0];
      const frag_a a1l = *(const frag_a*)&a_ml[cur][i1];

      frag_cd acc[4];
#pragma unroll
      for (int nt = 0; nt < 4; ++nt) {
        frag_cd a = {bacc[nt], bacc[nt], bacc[nt], bacc[nt]};
        a = __builtin_amdgcn_mfma_f32_16x16x32_f16(a0, bm0[nt], a, 0, 0, 0);
        a = __builtin_amdgcn_mfma_f32_16x16x32_f16(a1, bm1[nt], a, 0, 0, 0);
        a = __builtin_amdgcn_mfma_f32_16x16x32_f16(a0l, bm0[nt], a, 0, 0, 0);
        a = __builtin_amdgcn_mfma_f32_16x16x32_f16(a1l, bm1[nt], a, 0, 0, 0);
        if (use_x) a = __builtin_amdgcn_mfma_f32_16x16x16f16(xf[ch], bm2[nt], a, 0, 0, 0);
        acc[nt] = a;
      }

#pragma unroll
      for (int j = 0; j < 4; ++j) {
        const float gi = acc[0][j];
        const float gf = acc[1][j];
        const float gg = acc[2][j];
        const float go = acc[3][j];
        float c = c_st[ch * 4 + j];
        c = fmaf(sigmoid_pre(gf), c, sigmoid_pre(gi) * tanh_pre(gg));
        c_st[ch * 4 + j] = c;
        const float h = sigmoid_pre(go) * tanh_f(c);
        const int rr = ch * 16 + quad * 4 + j;
        const int idx = (((col >> 3) * kRows) + rr) * 8 + (col & 7);
        const _Float16 hh = (_Float16)h;
        a_mh[cur ^ 1][idx] = hh;
        a_ml[cur ^ 1][idx] = (_Float16)(h - (float)hh);  // lo residual
      }
    }
  };

  // ================= ENCODER =================
  load_gate_frags(enc_Whh, enc_Wih, enc_b);
  __syncthreads();  // plane init visible

  int cur = 0;
  frag_a2 xf[kChunks];
#pragma unroll 1
  for (int s = 0; s < kSrcLen; ++s) {
    load_xfrags(s, xf);
    lstm_step(cur, xf, true);
    __syncthreads();
    cur ^= 1;
  }

  // ================= DECODER =================
  // Step 1 uses x_last = src[:, -1, :] through the plain dec weights.
  load_gate_frags(dec_Whh, dec_Wih, dec_b);
  load_xfrags(kSrcLen - 1, xf);
  lstm_step(cur, xf, true);
  __syncthreads();
  cur ^= 1;

  // ---- fold the pred->x feedback into the recurrence (steps 2..10):
  // gates = h @ (Whh + Wih@fc_W)^T + (b + Wih@fc_b), all pre-scaled.
  // bm0/bm1 already hold scale*Whh; add scale*(Wih@fc_W) elementwise.
  // One-time, all loads L2-hot (fc_W 2.25KB, dec_Wih 9KB). bacc -> folded bias.
#pragma unroll 1
  for (int nt = 0; nt < 4; ++nt) {
    const float scale = (nt == 2) ? (2.0f * kLog2e) : kLog2e;
    const int n = nt * kH + col;
    float wih_s[kIn];
#pragma unroll
    for (int j = 0; j < kIn; ++j) wih_s[j] = scale * ldf(dec_Wih, n * kIn + j, isbf);
    frag_a f0 = bm0[nt], f1 = bm1[nt];
#pragma unroll 1
    for (int e = 0; e < 8; ++e) {
      const int k0 = quad * 8 + e;
      const int k1 = 32 + quad * 8 + e;
      float a0 = (float)f0[e], a1 = (float)f1[e];
#pragma unroll
      for (int j = 0; j < kIn; ++j) {
        a0 = fmaf(wih_s[j], ldf(fc_W, j * kH + k0, isbf), a0);
        a1 = fmaf(wih_s[j], ldf(fc_W, j * kH + k1, isbf), a1);
      }
      f0[e] = (_Float16)a0;
      f1[e] = (_Float16)a1;
    }
    bm0[nt] = f0;
    bm1[nt] = f1;
    float be = bacc[nt];  // scale * dec_b[n], already f32
#pragma unroll
    for (int j = 0; j < kIn; ++j) be = fmaf(wih_s[j], ldf(fc_b, j, isbf), be);
    bacc[nt] = be;
  }

  // fc head fragments (bm2 is dead now; RA reuses those regs).
  frag_a fm[2];
#pragma unroll
  for (int kt = 0; kt < 2; ++kt) {
    frag_a f;
#pragma unroll
    for (int j = 0; j < 8; ++j) {
      const int k = kt * 32 + quad * 8 + j;
      f[j] = (half < kIn) ? (_Float16)ldf(fc_W, half * kH + k, isbf) : (_Float16)0.0f;
    }
    fm[kt] = f;
  }
  const float fcb = (half < kIn) ? ldf(fc_b, half, isbf) : 0.0f;

  // fc head: wave w handles rows [w*16, w*16+16) of buf[cb]. Output-only.
  // hi plane only: pred error from dropping lo is ~7e-5 << bf16 out quantum.
  auto fc_head = [&](int t, int cb) {
    const int r = wave * 16 + half;
    const frag_a a0 = *(const frag_a*)&a_mh[cb][((0 * 4 + quad) * kRows + r) * 8];
    const frag_a a1 = *(const frag_a*)&a_mh[cb][((1 * 4 + quad) * kRows + r) * 8];
    frag_cd p = {fcb, fcb, fcb, fcb};
    p = __builtin_amdgcn_mfma_f32_16x16x32_f16(a0, fm[0], p, 0, 0, 0);
    p = __builtin_amdgcn_mfma_f32_16x16x32_f16(a1, fm[1], p, 0, 0, 0);
    if (half < kIn) {
#pragma unroll
      for (int j = 0; j < 4; ++j) {
        const int rr = wave * 16 + quad * 4 + j;
        const int oidx = (row0 + rr) * kOutW + t * kIn + half;
        if (isbf) ((__hip_bfloat16*)out)[oidx] = __float2bfloat16(p[j]);
        else ((float*)out)[oidx] = p[j];
      }
    }
  };

  // pred(0): h after decoder step 1 sits in buf[cur] (barrier'd above).
  fc_head(0, cur);

#pragma unroll 1
  for (int t = 1; t < kPredLen; ++t) {
    lstm_step(cur, nullptr, false);
    __syncthreads();
    cur ^= 1;
    fc_head(t, cur);
  }
}

extern "C" void kernel_launch(void* const* d_in, const int* in_sizes, int n_in,
                              void* d_out, int out_size, void* d_ws, size_t ws_size,
                              hipStream_t stream) {
  (void)n_in; (void)ws_size; (void)out_size;
  int* flag = (int*)d_ws;

  hipLaunchKernelGGL(detect_dtype_kernel, dim3(1), dim3(64), 0, stream,
                     (const uint16_t*)d_in[0], flag);

  const int b_total = in_sizes[0] / (kSrcLen * kIn);
  const int grid = b_total / kRows;  // B=65536 -> 1024 blocks = 4 per CU of work

  hipLaunchKernelGGL(lstm_seq2seq_kernel, dim3(grid), dim3(kThreads), 0, stream,
                     d_in[0], d_in[1], d_in[2], d_in[3], d_in[4], d_in[5],
                     d_in[6], d_in[7], d_in[8], d_out, flag);
}

// Round 7
// 258.390 us; speedup vs baseline: 1.3435x; 1.3287x over previous
//
#include <hip/hip_runtime.h>
#include <hip/hip_bf16.h>
#include <stdint.h>

namespace {
constexpr int kH = 64;
constexpr int kIn = 9;
constexpr int kSrcLen = 7;
constexpr int kPredLen = 10;
constexpr int kRows = 64;        // batch rows per block (r0-proven ILP: 4 chunks/wave)
constexpr int kThreads = 256;    // 4 waves: wave w owns gate-cols w*16..w*16+15
constexpr int kChunks = kRows / 16;    // 4 row-chunks per wave
constexpr int kOutW = kPredLen * kIn;  // 90
// A (h part): fragment-contiguous f16, 8 k-blocks (k 0..63), element
// (blk,row,e) at (blk*kRows+row)*8+e. Encoder x comes straight from GLOBAL
// as fragments; decoder feedback pred->x goes through a single 2 KB ax panel
// ax[row][e]: e 0..8 = pred (scattered by fc_head), e 9..15 = 0 (zero-init;
// bm2 weights are 0 there so any value x 0 = 0, but keep it clean).
constexpr int kABlk = 8;
constexpr int kASz = kABlk * kRows * 8;   // 4096 halves = 8192 B per buffer
constexpr int kAxSz = kRows * 16;         // 1024 halves = 2048 B, single buffer

constexpr float kLog2e = 1.4426950408889634f;

typedef __attribute__((ext_vector_type(8))) _Float16 frag_a;   // K=32 frag (4 VGPRs)
typedef __attribute__((ext_vector_type(4))) _Float16 frag_a2;  // K=16 frag (2 VGPRs)
typedef __attribute__((ext_vector_type(4))) float frag_cd;     // 4 fp32 acc

__device__ __forceinline__ float fast_rcp(float x) { return __builtin_amdgcn_rcpf(x); }
__device__ __forceinline__ float exp2_f(float x) { return __builtin_amdgcn_exp2f(x); }
// x PRE-SCALED by log2e (folded into weights): sigmoid = 1/(1+2^-x)
__device__ __forceinline__ float sigmoid_pre(float x) { return fast_rcp(1.0f + exp2_f(-x)); }
// x PRE-SCALED by 2*log2e: tanh = 1 - 2/(2^x + 1)
__device__ __forceinline__ float tanh_pre(float x) { return 1.0f - 2.0f * fast_rcp(exp2_f(x) + 1.0f); }
// unscaled input (cell state)
__device__ __forceinline__ float tanh_f(float x) { return tanh_pre(x * (2.0f * kLog2e)); }

__device__ __forceinline__ float ldf(const void* p, int i, int isbf) {
  if (isbf) {
    uint32_t w = ((uint32_t)((const uint16_t*)p)[i]) << 16;
    float f; __builtin_memcpy(&f, &w, 4); return f;
  }
  return ((const float*)p)[i];
}
}  // namespace

// Detect whether inputs are bf16 or fp32 by sampling src.
extern "C" __global__ void detect_dtype_kernel(const uint16_t* __restrict__ src_u16,
                                               int* __restrict__ flag) {
  const int t = threadIdx.x;
  int bad = 0;
  for (int i = t; i < 256; i += 64) {
    const uint16_t u = src_u16[i];
    const uint32_t e = (u >> 7) & 0xFF;
    const int plausible = (u == 0) || (e >= 100 && e <= 150);
    bad += !plausible;
  }
#pragma unroll
  for (int off = 32; off; off >>= 1) bad += __shfl_down(bad, off, 64);
  if (t == 0) *flag = (bad < 64) ? 1 : 0;
}

extern "C" __global__ void __launch_bounds__(kThreads)
// (4,8): min 4 waves/EU -> 128-unified-reg budget. THE ONLY PROVEN SPILL-FREE
// REGION for this family (r0: 60 arch + 64 acc, FETCH == inputs).
// ESTABLISHED FAILURES: (8,8) -> 1.5 GB scratch (r1); (5,8) -> 0.5 GB (r3);
// h-split at (4,8) -> 0.45 GB (r6, +16 transient VGPRs over the top).
// ACCURACY LEDGER: non-folded decoder = robust 3.9e-3 (r0, r2); folded
// decoder = codegen-roulette across the 1.42e-2 threshold (r3 pass, r4/r5
// fail) -> fold branch abandoned. This round: r0 structure + only the
// proven-passing cheapeners (log2e pre-scale r2; x-from-global r3/r6;
// f32 bias acc-init r6). Peak transient demand ~111 < 128.
__attribute__((amdgpu_waves_per_eu(4, 8)))
lstm_seq2seq_kernel(const void* __restrict__ src,
                    const void* __restrict__ enc_Wih,
                    const void* __restrict__ enc_Whh,
                    const void* __restrict__ enc_b,
                    const void* __restrict__ dec_Wih,
                    const void* __restrict__ dec_Whh,
                    const void* __restrict__ dec_b,
                    const void* __restrict__ fc_W,
                    const void* __restrict__ fc_b,
                    void* __restrict__ out,
                    const int* __restrict__ flag) {
  __shared__ __align__(16) _Float16 a_m[2][kASz];  // h, double-buffered, 16 KB
  __shared__ __align__(16) _Float16 ax[kAxSz];     // decoder pred->x panel, 2 KB

  const int tid = threadIdx.x;
  const int lane = tid & 63;
  const int wave = tid >> 6;       // 0..3
  const int quad = lane >> 4;
  const int half = lane & 15;
  const int row0 = blockIdx.x * kRows;
  const int isbf = *flag;  // grid-uniform
  const int col = wave * 16 + half;  // hidden column owned in activation phase

  // ---- init: h buffers zero (h0 == 0); ax zero (cols 9..15 stay 0) ----
  for (int i = tid; i < kASz; i += kThreads) {
    a_m[0][i] = (_Float16)0.0f;
    a_m[1][i] = (_Float16)0.0f;
  }
  for (int i = tid; i < kAxSz; i += kThreads) ax[i] = (_Float16)0.0f;

  // ---- persistent per-thread state: cell state for 4 chunks ----
  float c_st[4 * kChunks];
#pragma unroll
  for (int i = 0; i < 4 * kChunks; ++i) c_st[i] = 0.0f;

  // B fragments: nt = GATE TYPE (i,f,g,o), col = wave*16+half.
  // bm0/bm1[nt] = K-tiles 0,1 (Whh, K=32 each); bm2[nt] = K-tile 2 (Wih, K=16).
  // Bias lives in f32 bacc, added via MFMA acc-init (exact, no f16 rounding).
  // PRE-SCALED: sigmoid gates (i,f,o) by log2e, tanh gate (g) by 2*log2e.
  frag_a bm0[4], bm1[4];
  frag_a2 bm2[4];
  float bacc[4] = {0.f, 0.f, 0.f, 0.f};

  auto load_gate_frags = [&](const void* Whh, const void* Wih, const void* bv) {
#pragma unroll
    for (int nt = 0; nt < 4; ++nt) {
      const float scale = (nt == 2) ? (2.0f * kLog2e) : kLog2e;
      const int n = nt * kH + col;
      frag_a f0, f1;
#pragma unroll
      for (int j = 0; j < 8; ++j) {
        f0[j] = (_Float16)(scale * ldf(Whh, n * kH + (quad * 8 + j), isbf));
        f1[j] = (_Float16)(scale * ldf(Whh, n * kH + (32 + quad * 8 + j), isbf));
      }
      bm0[nt] = f0;
      bm1[nt] = f1;
      frag_a2 f2;
#pragma unroll
      for (int j = 0; j < 4; ++j) {
        const int k2 = quad * 4 + j;  // 0..15, global k = 64 + k2
        float v = 0.0f;
        if (k2 < kIn) v = ldf(Wih, n * kIn + k2, isbf);
        f2[j] = (_Float16)(scale * v);
      }
      bm2[nt] = f2;
      bacc[nt] = scale * ldf(bv, n, isbf);  // f32 bias via acc-init (exact)
    }
  };

  // x fragments straight from global (no LDS round-trip). Lane (quad,half) of
  // chunk ch supplies A[row=ch*16+half][k=quad*4+j]; k 0..8 = x, rest 0.
  // src tile is 16KB/block -> L2-hot after first touch.
  auto load_xfrags = [&](int s, frag_a2 (&xf)[kChunks]) {
#pragma unroll
    for (int ch = 0; ch < kChunks; ++ch) {
      frag_a2 f = {(_Float16)0.f, (_Float16)0.f, (_Float16)0.f, (_Float16)0.f};
      const int r = row0 + ch * 16 + half;
      const int base = r * (kSrcLen * kIn) + s * kIn;
      if (quad < 2) {
#pragma unroll
        for (int j = 0; j < 4; ++j) f[j] = (_Float16)ldf(src, base + quad * 4 + j, isbf);
      } else if (quad == 2) {
        f[0] = (_Float16)ldf(src, base + 8, isbf);  // x8
      }
      xf[ch] = f;
    }
  };

  // One LSTM step: read h from buf[cur], write h' into buf[cur^1]. No barrier
  // inside. x source: xf fragments (encoder / dec step 1) or the ax panel
  // (decoder feedback steps). Both paths use bm2; bias comes from bacc.
  auto lstm_step = [&](int cur, const frag_a2* xf) {
#pragma unroll 1
    for (int ch = 0; ch < kChunks; ++ch) {
      const int r = ch * 16 + half;
      const frag_a a0 = *(const frag_a*)&a_m[cur][((0 * 4 + quad) * kRows + r) * 8];
      const frag_a a1 = *(const frag_a*)&a_m[cur][((1 * 4 + quad) * kRows + r) * 8];
      const frag_a2 a2 = xf ? xf[ch] : *(const frag_a2*)&ax[r * 16 + quad * 4];

      frag_cd acc[4];
#pragma unroll
      for (int nt = 0; nt < 4; ++nt) {
        frag_cd a = {bacc[nt], bacc[nt], bacc[nt], bacc[nt]};
        a = __builtin_amdgcn_mfma_f32_16x16x32_f16(a0, bm0[nt], a, 0, 0, 0);
        a = __builtin_amdgcn_mfma_f32_16x16x32_f16(a1, bm1[nt], a, 0, 0, 0);
        a = __builtin_amdgcn_mfma_f32_16x16x16f16(a2, bm2[nt], a, 0, 0, 0);
        acc[nt] = a;
      }

      // activations fully in registers: acc[0..3][j] = (gi,gf,gg,go) for
      // (row = ch*16 + quad*4 + j, col); gate values pre-scaled by log2e(s).
#pragma unroll
      for (int j = 0; j < 4; ++j) {
        const float gi = acc[0][j];
        const float gf = acc[1][j];
        const float gg = acc[2][j];
        const float go = acc[3][j];
        float c = c_st[ch * 4 + j];
        c = fmaf(sigmoid_pre(gf), c, sigmoid_pre(gi) * tanh_pre(gg));
        c_st[ch * 4 + j] = c;
        const float h = sigmoid_pre(go) * tanh_f(c);
        const int rr = ch * 16 + quad * 4 + j;
        a_m[cur ^ 1][(((col >> 3) * kRows) + rr) * 8 + (col & 7)] = (_Float16)h;
      }
    }
  };

  // ================= ENCODER =================
  load_gate_frags(enc_Whh, enc_Wih, enc_b);
  __syncthreads();  // init visible

  int cur = 0;
  frag_a2 xf[kChunks];
#pragma unroll 1
  for (int s = 0; s < kSrcLen; ++s) {
    load_xfrags(s, xf);
    lstm_step(cur, xf);
    __syncthreads();
    cur ^= 1;
  }

  // ================= DECODER =================
  // Step 1 uses x_last = src[:, -1, :] through the plain dec weights.
  load_gate_frags(dec_Whh, dec_Wih, dec_b);
  load_xfrags(kSrcLen - 1, xf);
  lstm_step(cur, xf);
  __syncthreads();
  cur ^= 1;

  // fc head fragments; bias f32.
  frag_a fm[2];
#pragma unroll
  for (int kt = 0; kt < 2; ++kt) {
    frag_a f;
#pragma unroll
    for (int j = 0; j < 8; ++j) {
      const int k = kt * 32 + quad * 8 + j;
      f[j] = (half < kIn) ? (_Float16)ldf(fc_W, half * kH + k, isbf) : (_Float16)0.0f;
    }
    fm[kt] = f;
  }
  const float fcb = (half < kIn) ? ldf(fc_b, half, isbf) : 0.0f;

  // fc head: wave w handles rows [w*16, w*16+16) of buf[cb]: writes pred to
  // out AND scatters it into the ax panel (the x of the next decoder step).
  auto fc_head = [&](int t, int cb) {
    const int r = wave * 16 + half;
    const frag_a a0 = *(const frag_a*)&a_m[cb][((0 * 4 + quad) * kRows + r) * 8];
    const frag_a a1 = *(const frag_a*)&a_m[cb][((1 * 4 + quad) * kRows + r) * 8];
    frag_cd p = {fcb, fcb, fcb, fcb};
    p = __builtin_amdgcn_mfma_f32_16x16x32_f16(a0, fm[0], p, 0, 0, 0);
    p = __builtin_amdgcn_mfma_f32_16x16x32_f16(a1, fm[1], p, 0, 0, 0);
    if (half < kIn) {
#pragma unroll
      for (int j = 0; j < 4; ++j) {
        const int rr = wave * 16 + quad * 4 + j;
        const float pred = p[j];
        const int oidx = (row0 + rr) * kOutW + t * kIn + half;
        if (isbf) ((__hip_bfloat16*)out)[oidx] = __float2bfloat16(pred);
        else ((float*)out)[oidx] = pred;
        ax[rr * 16 + half] = (_Float16)pred;  // feedback x for next step
      }
    }
  };

  // pred(0): h after decoder step 1 sits in a_m[cur] (barrier'd above).
  fc_head(0, cur);
  __syncthreads();  // ax scatter visible before next step reads it

#pragma unroll 1
  for (int t = 1; t < kPredLen; ++t) {
    lstm_step(cur, nullptr);   // reads a_m[cur] + ax panel
    __syncthreads();           // h' + (write-after-read on ax) ordered
    cur ^= 1;
    fc_head(t, cur);
    __syncthreads();           // ax scatter visible
  }
}

extern "C" void kernel_launch(void* const* d_in, const int* in_sizes, int n_in,
                              void* d_out, int out_size, void* d_ws, size_t ws_size,
                              hipStream_t stream) {
  (void)n_in; (void)ws_size; (void)out_size;
  int* flag = (int*)d_ws;

  hipLaunchKernelGGL(detect_dtype_kernel, dim3(1), dim3(64), 0, stream,
                     (const uint16_t*)d_in[0], flag);

  const int b_total = in_sizes[0] / (kSrcLen * kIn);
  const int grid = b_total / kRows;  // B=65536 -> 1024 blocks = 4 per CU of work

  hipLaunchKernelGGL(lstm_seq2seq_kernel, dim3(grid), dim3(kThreads), 0, stream,
                     d_in[0], d_in[1], d_in[2], d_in[3], d_in[4], d_in[5],
                     d_in[6], d_in[7], d_in[8], d_out, flag);
}

// Round 8
// 212.425 us; speedup vs baseline: 1.6342x; 1.2164x over previous
//
#include <hip/hip_runtime.h>
#include <hip/hip_bf16.h>
#include <stdint.h>

namespace {
constexpr int kH = 64;
constexpr int kIn = 9;
constexpr int kSrcLen = 7;
constexpr int kPredLen = 10;
constexpr int kRows = 64;        // batch rows per block
constexpr int kThreads = 256;    // 4 waves
constexpr int kOutW = kPredLen * kIn;  // 90
// A (h part): fragment-contiguous f16, 8 k-blocks (k 0..63), element
// (blk,row,e) at (blk*64+row)*8+e. x/bias live in a separate 16-wide panel
// ax[row][e]: e 0..8 = x, e 9 = 1.0 (bias), 10..15 = 0 (K-tile 2 = 16x16x16).
constexpr int kABlk = 8;
constexpr int kASz = kABlk * kRows * 8;   // 4096 halves = 8192 B per buffer
constexpr int kAxSz = kRows * 16;         // 1024 halves = 2048 B per buffer

constexpr float kLog2e = 1.4426950408889634f;
constexpr float k2Log2e = 2.8853900817779268f;

typedef __attribute__((ext_vector_type(8))) _Float16 frag_a;   // K=32 frag (4 VGPRs)
typedef __attribute__((ext_vector_type(4))) _Float16 frag_a2;  // K=16 frag (2 VGPRs)
typedef __attribute__((ext_vector_type(4))) float frag_cd;     // 4 fp32 acc

__device__ __forceinline__ float fast_rcp(float x) { return __builtin_amdgcn_rcpf(x); }
__device__ __forceinline__ float exp2_f(float x) { return __builtin_amdgcn_exp2f(x); }

__device__ __forceinline__ float ldf(const void* p, int i, int isbf) {
  if (isbf) {
    uint32_t w = ((uint32_t)((const uint16_t*)p)[i]) << 16;
    float f; __builtin_memcpy(&f, &w, 4); return f;
  }
  return ((const float*)p)[i];
}
}  // namespace

// Detect whether inputs are bf16 or fp32 by sampling src.
extern "C" __global__ void detect_dtype_kernel(const uint16_t* __restrict__ src_u16,
                                               int* __restrict__ flag) {
  const int t = threadIdx.x;
  int bad = 0;
  for (int i = t; i < 256; i += 64) {
    const uint16_t u = src_u16[i];
    const uint32_t e = (u >> 7) & 0xFF;
    const int plausible = (u == 0) || (e >= 100 && e <= 150);
    bad += !plausible;
  }
#pragma unroll
  for (int off = 32; off; off >>= 1) bad += __shfl_down(bad, off, 64);
  if (t == 0) *flag = (bad < 64) ? 1 : 0;
}

extern "C" __global__ void __launch_bounds__(kThreads)
// (4,4): r0-PROVEN point — 4 waves/EU, 128-unified budget, compiled 60 arch +
// 64 acc SPILL-FREE (FETCH == inputs). Register-structure law from this
// session: every variant adding >=4 persistent regs spilled hard:
// (8,8) r1 -> 1.5 GB scratch; (5,8) r3 -> 0.5 GB; h-split r6 -> 0.45 GB;
// xf-global+bacc r7 -> 0.2 GB. This round patches r0 ONLY where the register
// structure is provably unchanged: (a) log2e folded into the SAME f16 weight
// values at load time (r2-proven, absmax 3.9e-3); (b) fused-rcp activations
// (pure f32 arithmetic, 10 -> 7 trans ops/element). ACCURACY LEDGER: the
// folded-decoder family straddles the 1.42e-2 threshold (r3 pass, r4/r5
// fail) -> abandoned; non-folded (this) is robust at 3.9e-3.
__attribute__((amdgpu_waves_per_eu(4, 4)))
lstm_seq2seq_kernel(const void* __restrict__ src,
                    const void* __restrict__ enc_Wih,
                    const void* __restrict__ enc_Whh,
                    const void* __restrict__ enc_b,
                    const void* __restrict__ dec_Wih,
                    const void* __restrict__ dec_Whh,
                    const void* __restrict__ dec_b,
                    const void* __restrict__ fc_W,
                    const void* __restrict__ fc_b,
                    void* __restrict__ out,
                    const int* __restrict__ flag) {
  __shared__ __align__(16) _Float16 a_m[2][kASz];   // h part, 2 x 8192 B
  __shared__ __align__(16) _Float16 ax[2][kAxSz];   // x|bias panel, 2 x 2048 B

  const int tid = threadIdx.x;
  const int lane = tid & 63;
  const int wave = tid >> 6;
  const int quad = lane >> 4;
  const int half = lane & 15;
  const int row0 = blockIdx.x * kRows;
  const int isbf = *flag;  // grid-uniform
  const int col = wave * 16 + half;  // hidden column owned in activation phase

  // ---- init: h buffers zero; ax zero except bias column e=9 = 1.0 ----
  for (int i = tid; i < kASz; i += kThreads) {
    a_m[0][i] = (_Float16)0.0f;
    a_m[1][i] = (_Float16)0.0f;
  }
  for (int i = tid; i < kAxSz; i += kThreads) {
    const _Float16 v = ((i & 15) == 9) ? (_Float16)1.0f : (_Float16)0.0f;
    ax[0][i] = v;
    ax[1][i] = v;
  }
  __syncthreads();

  // per-thread encoder staging slots (fixed across steps): items tid, tid+256,
  // tid+512 of the 576-element x panel; r = item/9, i = item%9.
  const int it1_on = (tid + 256 < kRows * kIn);
  const int it2_on = (tid + 512 < kRows * kIn);
  const int r_0 = tid / kIn, i_0 = tid - r_0 * kIn;
  const int r_1 = (tid + 256) / kIn, i_1 = (tid + 256) - r_1 * kIn;
  const int r_2 = (tid + 512) / kIn, i_2 = (tid + 512) - r_2 * kIn;
  const int lds0 = r_0 * 16 + i_0;
  const int lds1 = r_1 * 16 + i_1;
  const int lds2 = r_2 * 16 + i_2;
  const int g0 = (row0 + r_0) * (kSrcLen * kIn) + i_0;
  const int g1 = (row0 + r_1) * (kSrcLen * kIn) + i_1;
  const int g2 = (row0 + r_2) * (kSrcLen * kIn) + i_2;

  // stage x(step 0) into buf 0
  ax[0][lds0] = (_Float16)ldf(src, g0, isbf);
  if (it1_on) ax[0][lds1] = (_Float16)ldf(src, g1, isbf);
  if (it2_on) ax[0][lds2] = (_Float16)ldf(src, g2, isbf);

  // ---- persistent per-thread state ----
  float c_st[16];
#pragma unroll
  for (int i = 0; i < 16; ++i) c_st[i] = 0.0f;

  // B fragments: nt = GATE TYPE (i,f,g,o), col = wave*16+half.
  // bm0/bm1[nt] = K-tiles 0,1 (Whh, K=32 each); bm2[nt] = K-tile 2 (Wih+bias, K=16).
  // PRE-SCALED (r2-proven): sigmoid gates (i,f,o) by log2e, tanh gate (g) by
  // 2*log2e -> activations use raw v_exp_f32 (exp2) with no pre-multiply.
  frag_a bm0[4], bm1[4];
  frag_a2 bm2[4];
  frag_a fm[2];
  float fcb = 0.0f;

  auto load_gate_frags = [&](const void* Whh, const void* Wih, const void* bv) {
#pragma unroll
    for (int nt = 0; nt < 4; ++nt) {
      const float scale = (nt == 2) ? k2Log2e : kLog2e;
      const int n = nt * kH + col;
      frag_a f0, f1;
#pragma unroll
      for (int j = 0; j < 8; ++j) {
        f0[j] = (_Float16)(scale * ldf(Whh, n * kH + (quad * 8 + j), isbf));
        f1[j] = (_Float16)(scale * ldf(Whh, n * kH + (32 + quad * 8 + j), isbf));
      }
      bm0[nt] = f0;
      bm1[nt] = f1;
      frag_a2 f2;
#pragma unroll
      for (int j = 0; j < 4; ++j) {
        const int k2 = quad * 4 + j;  // 0..15, global k = 64 + k2
        float v = 0.0f;
        if (k2 < kIn) v = ldf(Wih, n * kIn + k2, isbf);
        else if (k2 == kIn) v = ldf(bv, n, isbf);  // bias column (A=1)
        f2[j] = (_Float16)(scale * v);
      }
      bm2[nt] = f2;
    }
  };

  // One LSTM step: read A from buf[cur], write h into buf[cur^1]. No barrier.
  // Gates arrive PRE-SCALED: gi,gf,go by L, gg by 2L. Fused-rcp activations:
  //   c' = [c*(1+ei)(eg+1) + (eg-1)(1+ef)] / [(1+ei)(eg+1)(1+ef)]   (1 rcp)
  //   h  = (t-1) / [(1+eo)(t+1)],  t = 2^(2L*c')                    (1 rcp)
  // Algebraically identical to sigmoid/tanh forms; 7 trans vs 10.
  auto lstm_step = [&](int cur) {
#pragma unroll 1
    for (int ch = 0; ch < 4; ++ch) {
      const int r = ch * 16 + half;
      const frag_a a0 = *(const frag_a*)&a_m[cur][((0 * 4 + quad) * kRows + r) * 8];
      const frag_a a1 = *(const frag_a*)&a_m[cur][((1 * 4 + quad) * kRows + r) * 8];
      const frag_a2 a2 = *(const frag_a2*)&ax[cur][r * 16 + quad * 4];

      frag_cd acc[4];
#pragma unroll
      for (int nt = 0; nt < 4; ++nt) {
        frag_cd a = {0.f, 0.f, 0.f, 0.f};
        a = __builtin_amdgcn_mfma_f32_16x16x32_f16(a0, bm0[nt], a, 0, 0, 0);
        a = __builtin_amdgcn_mfma_f32_16x16x32_f16(a1, bm1[nt], a, 0, 0, 0);
        a = __builtin_amdgcn_mfma_f32_16x16x16f16(a2, bm2[nt], a, 0, 0, 0);
        acc[nt] = a;
      }

      // activations fully in registers: acc[0..3][j] = (gi,gf,gg,go) for
      // (row = ch*16 + quad*4 + j, col)
#pragma unroll
      for (int j = 0; j < 4; ++j) {
        const float gi = acc[0][j];
        const float gf = acc[1][j];
        const float gg = acc[2][j];
        const float go = acc[3][j];
        const float ei = exp2_f(-gi);
        const float ef = exp2_f(-gf);
        const float eg = exp2_f(gg);
        const float eo = exp2_f(-go);
        const float c_old = c_st[ch * 4 + j];
        const float p1 = (1.0f + ei) * (eg + 1.0f);
        const float q = (eg - 1.0f) * (1.0f + ef);
        const float num = fmaf(c_old, p1, q);
        const float c = num * fast_rcp(p1 * (1.0f + ef));
        c_st[ch * 4 + j] = c;
        const float t = exp2_f(c * k2Log2e);
        const float h = (t - 1.0f) * fast_rcp((1.0f + eo) * (t + 1.0f));
        const int rr = ch * 16 + quad * 4 + j;
        a_m[cur ^ 1][(((col >> 3) * kRows) + rr) * 8 + (col & 7)] = (_Float16)h;
      }
    }
  };

  // ================= ENCODER =================
  load_gate_frags(enc_Whh, enc_Wih, enc_b);
  __syncthreads();  // x(0) + init visible

  int cur = 0;
#pragma unroll 1
  for (int s = 0; s < kSrcLen; ++s) {
    // prefetch next-step x BEFORE the step so L2 latency overlaps compute
    const int ns = (s + 1 < kSrcLen) ? s + 1 : kSrcLen - 1;
    const int off = ns * kIn;
    const float x0 = ldf(src, g0 + off, isbf);
    const float x1 = it1_on ? ldf(src, g1 + off, isbf) : 0.0f;
    const float x2 = it2_on ? ldf(src, g2 + off, isbf) : 0.0f;

    lstm_step(cur);

    ax[cur ^ 1][lds0] = (_Float16)x0;
    if (it1_on) ax[cur ^ 1][lds1] = (_Float16)x1;
    if (it2_on) ax[cur ^ 1][lds2] = (_Float16)x2;
    __syncthreads();
    cur ^= 1;
  }

  // ================= DECODER =================
  load_gate_frags(dec_Whh, dec_Wih, dec_b);
  // fc B fragments (K-tiles 0,1 = h only; bias via acc init); B cols 0..8.
  // fc weights NOT scaled (no activation on the head).
#pragma unroll
  for (int kt = 0; kt < 2; ++kt) {
    frag_a f;
#pragma unroll
    for (int j = 0; j < 8; ++j) {
      const int k = kt * 32 + quad * 8 + j;
      f[j] = (half < kIn) ? (_Float16)ldf(fc_W, half * kH + k, isbf) : (_Float16)0.0f;
    }
    fm[kt] = f;
  }
  fcb = (half < kIn) ? ldf(fc_b, half, isbf) : 0.0f;

#pragma unroll 1
  for (int t = 0; t < kPredLen; ++t) {
    lstm_step(cur);
    __syncthreads();
    cur ^= 1;

    // ---- fc head: wave w handles rows [w*16, w*16+16) of buf[cur] ----
    const int r = wave * 16 + half;
    const frag_a a0 = *(const frag_a*)&a_m[cur][((0 * 4 + quad) * kRows + r) * 8];
    const frag_a a1 = *(const frag_a*)&a_m[cur][((1 * 4 + quad) * kRows + r) * 8];
    frag_cd p = {fcb, fcb, fcb, fcb};
    p = __builtin_amdgcn_mfma_f32_16x16x32_f16(a0, fm[0], p, 0, 0, 0);
    p = __builtin_amdgcn_mfma_f32_16x16x32_f16(a1, fm[1], p, 0, 0, 0);

    if (half < kIn) {
#pragma unroll
      for (int j = 0; j < 4; ++j) {
        const int rr = wave * 16 + quad * 4 + j;
        const float pred = p[j];
        const int oidx = (row0 + rr) * kOutW + t * kIn + half;
        if (isbf) {
          ((__hip_bfloat16*)out)[oidx] = __float2bfloat16(pred);
        } else {
          ((float*)out)[oidx] = pred;
        }
        // feedback x into the panel the next step reads (bias col untouched)
        ax[cur][rr * 16 + half] = (_Float16)pred;
      }
    }
    __syncthreads();
  }
}

extern "C" void kernel_launch(void* const* d_in, const int* in_sizes, int n_in,
                              void* d_out, int out_size, void* d_ws, size_t ws_size,
                              hipStream_t stream) {
  (void)n_in; (void)ws_size; (void)out_size;
  int* flag = (int*)d_ws;

  hipLaunchKernelGGL(detect_dtype_kernel, dim3(1), dim3(64), 0, stream,
                     (const uint16_t*)d_in[0], flag);

  const int b_total = in_sizes[0] / (kSrcLen * kIn);
  const int grid = b_total / kRows;  // B=65536 -> 1024 blocks = 4 per CU

  hipLaunchKernelGGL(lstm_seq2seq_kernel, dim3(grid), dim3(kThreads), 0, stream,
                     d_in[0], d_in[1], d_in[2], d_in[3], d_in[4], d_in[5],
                     d_in[6], d_in[7], d_in[8], d_out, flag);
}